// Round 9
// baseline (103.015 us; speedup 1.0000x reference)
//
#include <hip/hip_runtime.h>

#define DIM 64
#define TILE_B 9
#define TILE (1 << TILE_B)     // 512 nodes per tile
#define CAPT 8192              // edge slots per tile
#define CHUNK 2048             // edges per partition block
#define MAXNT 512              // max tiles supported by LDS arrays

typedef float f32x4 __attribute__((ext_vector_type(4)));
typedef unsigned int u32x4 __attribute__((ext_vector_type(4)));

__global__ void zero_gcur_kernel(int* __restrict__ g) {
    g[threadIdx.x + blockIdx.x * blockDim.x] = 0;   // 2*MAXNT ints, 4 blocks x 256
}

// ---------- Phase 1: tile partition (src-side and dst-side) ----------
__global__ void partition_kernel(const int* __restrict__ src, const int* __restrict__ dst,
                                 int* __restrict__ gcur_d, int* __restrict__ gcur_s,
                                 unsigned int* __restrict__ ebuf,
                                 unsigned short* __restrict__ sbuf,
                                 int n_edges, int nt) {
    __shared__ int cnt_d[MAXNT];
    __shared__ int cnt_s[MAXNT];
    const int tid = threadIdx.x;
    for (int k = tid; k < nt; k += blockDim.x) { cnt_d[k] = 0; cnt_s[k] = 0; }
    __syncthreads();

    const int base = blockIdx.x * CHUNK;
    const int rem = min(CHUNK, n_edges - base);
    const int rem4 = rem >> 2;
    const int4* src4 = reinterpret_cast<const int4*>(src + base);
    const int4* dst4 = reinterpret_cast<const int4*>(dst + base);

    int4 sv[2], dv[2];
    bool ok[2];
    #pragma unroll
    for (int k = 0; k < 2; ++k) {
        int i4 = tid + k * 256;
        ok[k] = (i4 < rem4);
        if (ok[k]) { sv[k] = src4[i4]; dv[k] = dst4[i4]; }
    }
    #pragma unroll
    for (int k = 0; k < 2; ++k) {
        if (ok[k]) {
            atomicAdd(&cnt_d[dv[k].x >> TILE_B], 1); atomicAdd(&cnt_s[sv[k].x >> TILE_B], 1);
            atomicAdd(&cnt_d[dv[k].y >> TILE_B], 1); atomicAdd(&cnt_s[sv[k].y >> TILE_B], 1);
            atomicAdd(&cnt_d[dv[k].z >> TILE_B], 1); atomicAdd(&cnt_s[sv[k].z >> TILE_B], 1);
            atomicAdd(&cnt_d[dv[k].w >> TILE_B], 1); atomicAdd(&cnt_s[sv[k].w >> TILE_B], 1);
        }
    }
    if (tid == 0) {
        for (int j = rem & ~3; j < rem; ++j) {
            atomicAdd(&cnt_d[dst[base + j] >> TILE_B], 1);
            atomicAdd(&cnt_s[src[base + j] >> TILE_B], 1);
        }
    }
    __syncthreads();
    for (int k = tid; k < nt; k += blockDim.x) {
        int cd = cnt_d[k];
        if (cd) cnt_d[k] = atomicAdd(&gcur_d[k], cd);
        int cs = cnt_s[k];
        if (cs) cnt_s[k] = atomicAdd(&gcur_s[k], cs);
    }
    __syncthreads();
    #pragma unroll
    for (int k = 0; k < 2; ++k) {
        if (ok[k]) {
            int ss[4] = {sv[k].x, sv[k].y, sv[k].z, sv[k].w};
            int dd[4] = {dv[k].x, dv[k].y, dv[k].z, dv[k].w};
            #pragma unroll
            for (int q = 0; q < 4; ++q) {
                int s = ss[q], d = dd[q];
                int td = d >> TILE_B;
                int p = atomicAdd(&cnt_d[td], 1);
                if (p < CAPT)
                    ebuf[(size_t)td * CAPT + p] =
                        ((unsigned int)(d & (TILE - 1)) << 23) | (unsigned int)s;
                int ts = s >> TILE_B;
                int p2 = atomicAdd(&cnt_s[ts], 1);
                if (p2 < CAPT)
                    sbuf[(size_t)ts * CAPT + p2] = (unsigned short)(s & (TILE - 1));
            }
        }
    }
    if (tid == 0) {
        for (int j = rem & ~3; j < rem; ++j) {
            int s = src[base + j], d = dst[base + j];
            int td = d >> TILE_B;
            int p = atomicAdd(&cnt_d[td], 1);
            if (p < CAPT)
                ebuf[(size_t)td * CAPT + p] =
                    ((unsigned int)(d & (TILE - 1)) << 23) | (unsigned int)s;
            int ts = s >> TILE_B;
            int p2 = atomicAdd(&cnt_s[ts], 1);
            if (p2 < CAPT)
                sbuf[(size_t)ts * CAPT + p2] = (unsigned short)(s & (TILE - 1));
        }
    }
}

// ---------- Phase 2 (fused): blocks [0,nt) build CSR per dst-tile;
//            blocks [nt,2nt) histogram src-tiles -> sq ----------
__global__ void tile_build_kernel(const unsigned int* __restrict__ ebuf,
                                  const unsigned short* __restrict__ sbuf,
                                  const int* __restrict__ gcur_d,
                                  const int* __restrict__ gcur_s,
                                  int* __restrict__ sorted_src,
                                  int* __restrict__ offsets,
                                  int* __restrict__ dcount,
                                  float* __restrict__ sq, int n_nodes, int nt) {
    __shared__ unsigned int h[TILE];
    __shared__ int off[TILE];
    __shared__ int stmp[256];
    const int tid = threadIdx.x;

    if (blockIdx.x >= nt) {
        // ---- sq role ----
        const int t = blockIdx.x - nt;
        for (int k = tid; k < TILE; k += blockDim.x) h[k] = 0u;
        __syncthreads();
        const int ne = min(gcur_s[t], CAPT);
        const unsigned short* p = sbuf + (size_t)t * CAPT;
        for (int j = tid; j < ne; j += blockDim.x) atomicAdd(&h[p[j]], 1u);
        __syncthreads();
        const int base = t << TILE_B;
        for (int k = tid; k < TILE; k += blockDim.x) {
            int node = base + k;
            if (node < n_nodes) sq[node] = rsqrtf((float)h[k]);
        }
        return;
    }

    // ---- CSR role ----
    const int t = blockIdx.x;
    for (int k = tid; k < TILE; k += blockDim.x) h[k] = 0u;
    __syncthreads();
    const int ne = min(gcur_d[t], CAPT);
    const unsigned int* p = ebuf + (size_t)t * CAPT;
    for (int j = tid; j < ne; j += blockDim.x) atomicAdd(&h[p[j] >> 23], 1u);
    __syncthreads();
    int v0 = (int)h[2 * tid];
    int v1 = (int)h[2 * tid + 1];
    int pair = v0 + v1;
    stmp[tid] = pair;
    __syncthreads();
    for (int o = 1; o < 256; o <<= 1) {
        int x = (tid >= o) ? stmp[tid - o] : 0;
        __syncthreads();
        stmp[tid] += x;
        __syncthreads();
    }
    int excl = stmp[tid] - pair;
    off[2 * tid] = excl;
    off[2 * tid + 1] = excl + v0;
    const int base = t << TILE_B;
    {
        int n0 = base + 2 * tid;
        if (n0 < n_nodes) { offsets[n0] = t * CAPT + excl;      dcount[n0] = v0; }
        int n1 = n0 + 1;
        if (n1 < n_nodes) { offsets[n1] = t * CAPT + excl + v0; dcount[n1] = v1; }
    }
    __syncthreads();
    for (int k = tid; k < TILE; k += blockDim.x) h[k] = (unsigned int)off[k];
    __syncthreads();
    for (int j = tid; j < ne; j += blockDim.x) {
        unsigned int e = p[j];
        int dlo = (int)(e >> 23);
        int pos = (int)atomicAdd(&h[dlo], 1u);
        sorted_src[(size_t)t * CAPT + pos] = (int)(e & 0x7fffffu);
    }
}

// ---------- bf16 pre-scaled table ----------
__global__ void scale_bf16_kernel(const float* __restrict__ embed, const float* __restrict__ sq,
                                  unsigned short* __restrict__ table, int n8) {
    int i = blockIdx.x * blockDim.x + threadIdx.x;
    if (i >= n8) return;
    float s = sq[i >> 3];
    const f32x4* p = reinterpret_cast<const f32x4*>(embed) + (size_t)i * 2;
    f32x4 v0 = __builtin_nontemporal_load(p);
    f32x4 v1 = __builtin_nontemporal_load(p + 1);
    float vals[8] = {v0.x, v0.y, v0.z, v0.w, v1.x, v1.y, v1.z, v1.w};
    unsigned int w[4];
    #pragma unroll
    for (int k = 0; k < 4; ++k) {
        unsigned int lo = __float_as_uint(vals[2 * k] * s);
        unsigned int hi = __float_as_uint(vals[2 * k + 1] * s);
        lo += 0x7fffu + ((lo >> 16) & 1u);
        hi += 0x7fffu + ((hi >> 16) & 1u);
        w[k] = (lo >> 16) | (hi & 0xffff0000u);
    }
    u32x4 o = {w[0], w[1], w[2], w[3]};
    __builtin_nontemporal_store(o, reinterpret_cast<u32x4*>(table) + i);
}

// ---------- aggregate: wave per node, CSR, bf16 table ----------
// sorted_src loads and out stores are nontemporal (read/write-once streams)
// so they don't evict the table from per-XCD L2.
__global__ void aggregate_csr_kernel(const unsigned short* __restrict__ table,
                                     const float* __restrict__ sq,
                                     const int* __restrict__ sorted_src,
                                     const int* __restrict__ offsets,
                                     const int* __restrict__ dcount,
                                     float* __restrict__ out, int n_nodes) {
    int gid = blockIdx.x * blockDim.x + threadIdx.x;
    int node = gid >> 6;
    if (node >= n_nodes) return;
    int lane = threadIdx.x & 63;
    int g = lane >> 3;
    int c = lane & 7;
    int start = offsets[node];
    int cnt = dcount[node];
    float a0 = 0.f, a1 = 0.f, a2 = 0.f, a3 = 0.f, a4 = 0.f, a5 = 0.f, a6 = 0.f, a7 = 0.f;
    for (int k = g; k < cnt; k += 8) {
        int s = __builtin_nontemporal_load(&sorted_src[start + k]);
        u32x4 raw = *reinterpret_cast<const u32x4*>(table + (size_t)s * DIM + c * 8);
        a0 += __uint_as_float(raw.x << 16);
        a1 += __uint_as_float(raw.x & 0xffff0000u);
        a2 += __uint_as_float(raw.y << 16);
        a3 += __uint_as_float(raw.y & 0xffff0000u);
        a4 += __uint_as_float(raw.z << 16);
        a5 += __uint_as_float(raw.z & 0xffff0000u);
        a6 += __uint_as_float(raw.w << 16);
        a7 += __uint_as_float(raw.w & 0xffff0000u);
    }
    #pragma unroll
    for (int m = 8; m <= 32; m <<= 1) {
        a0 += __shfl_xor(a0, m, 64); a1 += __shfl_xor(a1, m, 64);
        a2 += __shfl_xor(a2, m, 64); a3 += __shfl_xor(a3, m, 64);
        a4 += __shfl_xor(a4, m, 64); a5 += __shfl_xor(a5, m, 64);
        a6 += __shfl_xor(a6, m, 64); a7 += __shfl_xor(a7, m, 64);
    }
    if (g == 0) {
        float sn = sq[node];
        float* o = out + (size_t)node * DIM + c * 8;
        f32x4 r0 = {a0 * sn, a1 * sn, a2 * sn, a3 * sn};
        f32x4 r1 = {a4 * sn, a5 * sn, a6 * sn, a7 * sn};
        __builtin_nontemporal_store(r0, reinterpret_cast<f32x4*>(o));
        __builtin_nontemporal_store(r1, reinterpret_cast<f32x4*>(o) + 1);
    }
}

// ---------- fallback path (tiny ws or huge n_nodes) ----------
__global__ void sdeg_atomic_kernel(const int* __restrict__ src, int* __restrict__ sdeg,
                                   int n_edges) {
    int i = blockIdx.x * blockDim.x + threadIdx.x;
    if (i < n_edges) atomicAdd(&sdeg[src[i]], 1);
}
__global__ void sq_from_sdeg_kernel(const int* __restrict__ sdeg, float* __restrict__ sq, int n) {
    int i = blockIdx.x * blockDim.x + threadIdx.x;
    if (i < n) sq[i] = rsqrtf((float)sdeg[i]);
}
__global__ void build_ll_kernel(const int* __restrict__ src, const int* __restrict__ dst,
                                int* __restrict__ head, int2* __restrict__ list, int n_edges) {
    int i = blockIdx.x * blockDim.x + threadIdx.x;
    if (i >= n_edges) return;
    int s = src[i];
    int d = dst[i];
    int prev = atomicExch(&head[d], i);
    list[i] = make_int2(prev, s);
}
__global__ void aggregate_ll_f32_kernel(const float* __restrict__ embed,
                                        const float* __restrict__ sq,
                                        const int* __restrict__ head,
                                        const int2* __restrict__ list,
                                        float* __restrict__ out, int n_nodes) {
    int gid = blockIdx.x * blockDim.x + threadIdx.x;
    int node = gid >> 3;
    if (node >= n_nodes) return;
    int c = gid & 7;
    int cur = head[node];
    float4 A0 = {0.f, 0.f, 0.f, 0.f}, A1 = {0.f, 0.f, 0.f, 0.f};
    while (cur >= 0) {
        int2 v = list[cur];
        cur = v.x;
        int s = v.y;
        float sc = sq[s];
        const float4* row = reinterpret_cast<const float4*>(embed + (size_t)s * DIM + c * 8);
        float4 v0 = row[0], v1 = row[1];
        A0.x += v0.x * sc; A0.y += v0.y * sc; A0.z += v0.z * sc; A0.w += v0.w * sc;
        A1.x += v1.x * sc; A1.y += v1.y * sc; A1.z += v1.z * sc; A1.w += v1.w * sc;
    }
    float sn = sq[node];
    float4 r0 = {A0.x * sn, A0.y * sn, A0.z * sn, A0.w * sn};
    float4 r1 = {A1.x * sn, A1.y * sn, A1.z * sn, A1.w * sn};
    float4* o = reinterpret_cast<float4*>(out + (size_t)node * DIM + c * 8);
    o[0] = r0; o[1] = r1;
}

static inline size_t align16(size_t x) { return (x + 15) & ~(size_t)15; }

extern "C" void kernel_launch(void* const* d_in, const int* in_sizes, int n_in,
                              void* d_out, int out_size, void* d_ws, size_t ws_size,
                              hipStream_t stream) {
    const float* embed = (const float*)d_in[0];
    const int*   src   = (const int*)d_in[1];
    const int*   dst   = (const int*)d_in[2];
    float*       out   = (float*)d_out;

    const int n_nodes = in_sizes[0] / DIM;
    const int n_edges = in_sizes[1];
    const int nt = (n_nodes + TILE - 1) >> TILE_B;
    const int tb = 256;

    size_t o_gcur_d = 0;
    size_t o_gcur_s = o_gcur_d + MAXNT * 4;
    size_t o_sq     = o_gcur_s + MAXNT * 4;
    size_t o_dcount = align16(o_sq + (size_t)n_nodes * 4);
    size_t o_off    = align16(o_dcount + (size_t)n_nodes * 4);
    size_t o_A      = align16(o_off + (size_t)n_nodes * 4);
    size_t A_bytes  = (size_t)nt * CAPT * 4;
    size_t table_b  = (size_t)n_nodes * DIM * 2;
    if (table_b > A_bytes) A_bytes = table_b;
    size_t o_B      = align16(o_A + A_bytes);
    size_t B_bytes  = (size_t)nt * CAPT * 4;
    size_t need     = o_B + B_bytes;

    const bool fast = (nt <= MAXNT) && (n_nodes <= (1 << 23)) && (ws_size >= need);

    if (fast) {
        char* ws = (char*)d_ws;
        int* gcur_d = (int*)(ws + o_gcur_d);
        int* gcur_s = (int*)(ws + o_gcur_s);
        float* sq   = (float*)(ws + o_sq);
        int* dcount = (int*)(ws + o_dcount);
        int* offsets= (int*)(ws + o_off);
        unsigned int*   ebuf  = (unsigned int*)(ws + o_A);
        unsigned short* table = (unsigned short*)(ws + o_A);
        unsigned short* sbuf  = (unsigned short*)(ws + o_B);
        int* sorted_src = (int*)(ws + o_B);

        zero_gcur_kernel<<<4, 256, 0, stream>>>(gcur_d);   // zeroes gcur_d + gcur_s

        const int g1 = (n_edges + CHUNK - 1) / CHUNK;
        partition_kernel<<<g1, tb, 0, stream>>>(src, dst, gcur_d, gcur_s, ebuf, sbuf,
                                                n_edges, nt);
        tile_build_kernel<<<2 * nt, tb, 0, stream>>>(ebuf, sbuf, gcur_d, gcur_s,
                                                     sorted_src, offsets, dcount,
                                                     sq, n_nodes, nt);
        const int n8 = n_nodes * (DIM / 8);
        scale_bf16_kernel<<<(n8 + tb - 1) / tb, tb, 0, stream>>>(embed, sq, table, n8);
        const long long at = (long long)n_nodes * 64;
        aggregate_csr_kernel<<<(int)((at + tb - 1) / tb), tb, 0, stream>>>(
            table, sq, sorted_src, offsets, dcount, out, n_nodes);
    } else {
        int*   head = (int*)d_ws;
        float* sq   = (float*)(head + n_nodes);
        int*   sdeg = (int*)(sq + n_nodes);
        int2*  list = (int2*)(sdeg + n_nodes);
        (void)hipMemsetAsync(head, 0xFF, (size_t)n_nodes * 4, stream);
        (void)hipMemsetAsync(sdeg, 0, (size_t)n_nodes * 4, stream);
        sdeg_atomic_kernel<<<(n_edges + tb - 1) / tb, tb, 0, stream>>>(src, sdeg, n_edges);
        sq_from_sdeg_kernel<<<(n_nodes + tb - 1) / tb, tb, 0, stream>>>(sdeg, sq, n_nodes);
        build_ll_kernel<<<(n_edges + tb - 1) / tb, tb, 0, stream>>>(src, dst, head,
                                                                    list, n_edges);
        const int at = n_nodes * 8;
        aggregate_ll_f32_kernel<<<(at + tb - 1) / tb, tb, 0, stream>>>(
            embed, sq, head, list, out, n_nodes);
    }
}